// Round 1
// 1284.137 us; speedup vs baseline: 1.0471x; 1.0471x over previous
//
#include <hip/hip_runtime.h>

// SFNO block on MI355X. All heavy stages as bf16 MFMA GEMMs (C = A * B^T),
// fp32 accumulate, 128x128 tiles, global_load_lds staging, XOR-swizzled LDS.
// Fused dual/complex product modes. Sizes: C=256, NLAT=256, NLON=512, L=256,
// M=257 (rfft rows padded to 384, irfft K padded to 288), NREF=64.

typedef __bf16 bf16x8 __attribute__((ext_vector_type(8)));
typedef float f32x4 __attribute__((ext_vector_type(4)));
typedef unsigned short u16;
typedef unsigned int u32;

__device__ __forceinline__ u16 f2b(float f){
  u32 u = __float_as_uint(f);
  u32 r = (u + 0x7FFFu + ((u >> 16) & 1u)) >> 16;  // round-to-nearest-even
  return (u16)r;
}
__device__ __forceinline__ float b2f(u16 h){
  return __uint_as_float(((u32)h) << 16);
}
// tanh-form gelu: v*sigmoid(2u), u = sqrt(2/pi)*(v + 0.044715 v^3).
// One v_exp_f32 + one v_rcp_f32 (~8 VALU) vs ~60 for ocml erff.
// |gelu_tanh - gelu_erf| < ~1e-3 abs, far below bf16 rounding of the result.
__device__ __forceinline__ float gelu_fast(float v){
  float u2 = v * (1.5957691216057308f + 0.07135481627260025f * v * v);  // 2u
  float e  = __expf(-u2);                       // e^{-2u}
  return v * __builtin_amdgcn_rcpf(1.0f + e);   // v * sigmoid(2u)
}

// ---------------- small precompute kernels ----------------

// forward DFT tables (384 x 512) bf16, rows >=257 zero: Tc=cos, Ts=-sin
__global__ __launch_bounds__(256) void k_ftab(u16* Tc, u16* Ts){
  int i = blockIdx.x*256 + threadIdx.x;
  if (i >= 384*512) return;
  int m = i >> 9, n = i & 511;
  if (m >= 257){ Tc[i]=0; Ts[i]=0; return; }
  int r = (m*n) & 511;
  float th = (float)r * (6.283185307179586f/512.0f);
  Tc[i] = f2b(cosf(th));
  Ts[i] = f2b(-sinf(th));
}
// inverse tables (512 x 288), cols >=257 zero. cm=1 for m in {0,256}, else 2; /512.
__global__ __launch_bounds__(256) void k_itab(u16* tr, u16* ti){
  int i = blockIdx.x*256 + threadIdx.x;
  if (i >= 512*288) return;
  int n = i / 288, m = i % 288;
  if (m >= 257){ tr[i]=0; ti[i]=0; return; }
  int r = (n*m) & 511;
  float th = (float)r * (6.283185307179586f/512.0f);
  float cm = (m==0 || m==256) ? (1.0f/512.0f) : (2.0f/512.0f);
  tr[i] = f2b(cm*cosf(th));
  ti[i] = f2b(-cm*sinf(th));
}
// lw[l,m,j] = legfuncs[l,m,j]*wquad[j] -> bf16
__global__ __launch_bounds__(256) void k_lw(const float* __restrict__ leg,
                                            const float* __restrict__ wq,
                                            u16* __restrict__ lw, int total){
  int i = blockIdx.x*256 + threadIdx.x;
  if (i >= total) return;
  lw[i] = f2b(leg[i]*wq[i & 255]);
}
// interpolated filters, scaled by sqrt(1+l)/256, layout (l,f,c) bf16.
// block = (f, c-chunk of 64); coalesced 16KB LDS stage of w[f, c0:c0+64, :].
__global__ __launch_bounds__(256) void k_interp(const float* __restrict__ wr,
                                                const float* __restrict__ wi,
                                                u16* __restrict__ Wr2, u16* __restrict__ Wi2){
  __shared__ float sr[64][65], si[64][65];
  const int f = blockIdx.x;
  const int c0 = blockIdx.y * 64;
  const float* gr = wr + ((long long)f*256 + c0)*64;
  const float* gi = wi + ((long long)f*256 + c0)*64;
  for (int t = threadIdx.x*4; t < 4096; t += 1024){
    float4 vr = *(const float4*)(gr + t);
    float4 vi = *(const float4*)(gi + t);
    int cc = t >> 6, k = t & 63;
    sr[cc][k]=vr.x; sr[cc][k+1]=vr.y; sr[cc][k+2]=vr.z; sr[cc][k+3]=vr.w;
    si[cc][k]=vi.x; si[cc][k+1]=vi.y; si[cc][k+2]=vi.z; si[cc][k+3]=vi.w;
  }
  __syncthreads();
  const int lane_c = threadIdx.x & 63;
  const int lgrp = threadIdx.x >> 6;
  for (int l = lgrp; l < 256; l += 4){
    float pos = (float)l * (63.0f/255.0f);
    int i0 = min((int)pos, 62);
    float fr = pos - (float)i0;
    float s = sqrtf(1.0f + (float)l) * (1.0f/256.0f);
    long long o = (long long)l*65536 + f*256 + c0 + lane_c;
    Wr2[o] = f2b((sr[lane_c][i0]*(1.0f-fr) + sr[lane_c][i0+1]*fr)*s);
    Wi2[o] = f2b((si[lane_c][i0]*(1.0f-fr) + si[lane_c][i0+1]*fr)*s);
  }
}

// ---------------- generic tiled transposes ----------------
template<bool DUAL>
__global__ __launch_bounds__(256)
void tr_f32b(const float* __restrict__ src, u16* __restrict__ dst, u16* __restrict__ copy,
             int R, int Cc, long long ir, long long ib, long long oc, long long ob){
  __shared__ float tile[32][33];
  const long long b = blockIdx.z;
  const int r0 = blockIdx.y*32, c0 = blockIdx.x*32;
  const int tx = threadIdx.x & 31, ty = threadIdx.x >> 5;
  const float* s = src + b*ib;
  #pragma unroll
  for (int rr = ty; rr < 32; rr += 8){
    int r = r0 + rr, c = c0 + tx;
    float v = 0.0f;
    if (r < R && c < Cc){
      v = s[(long long)r*ir + c];
      if (DUAL) copy[b*ib + (long long)r*ir + c] = f2b(v);
    }
    tile[rr][tx] = v;
  }
  __syncthreads();
  u16* d = dst + b*ob;
  #pragma unroll
  for (int cc = ty; cc < 32; cc += 8){
    int c = c0 + cc, r = r0 + tx;
    if (r < R && c < Cc) d[(long long)c*oc + r] = f2b(tile[tx][cc]);
  }
}
// bf16 transpose; zero-pads dst rows r in [R, Rpad)
__global__ __launch_bounds__(256)
void tr_b16(const u16* __restrict__ src, u16* __restrict__ dst,
            int R, int Rpad, int Cc, long long ir, long long ib, long long oc, long long ob){
  __shared__ u16 tile[32][34];
  const long long b = blockIdx.z;
  const int r0 = blockIdx.y*32, c0 = blockIdx.x*32;
  const int tx = threadIdx.x & 31, ty = threadIdx.x >> 5;
  const u16* s = src + b*ib;
  #pragma unroll
  for (int rr = ty; rr < 32; rr += 8){
    int r = r0 + rr, c = c0 + tx;
    tile[rr][tx] = (r < R && c < Cc) ? s[(long long)r*ir + c] : (u16)0;
  }
  __syncthreads();
  u16* d = dst + b*ob;
  #pragma unroll
  for (int cc = ty; cc < 32; cc += 8){
    int c = c0 + cc, r = r0 + tx;
    if (r < Rpad && c < Cc) d[(long long)c*oc + r] = tile[tx][cc];
  }
}

// ---------------- the 128x128 GEMM ----------------
// MODE 0: C0 = A0*B0^T
// MODE 1: C0 = A0*B0^T + A1*B1^T
// MODE 2: C0 = A0*B0^T ; C1 = A0*B1^T          (shared A)
// MODE 3: C0 = A0*B0^T ; C1 = A1*B0^T          (shared B)
// MODE 4: C0 = A0*B0^T - A1*B1^T ; C1 = A0*B1^T + A1*B0^T   (complex)
// EPI 0: bf16 raw; 1: bf16 gelu(v); 2: bf16 gelu(v+bias); 3: bf16 gelu(v+bias)+addsrc
struct GemmP {
  const u16 *A0, *A1, *B0, *B1;
  u16 *C0, *C1;
  const float *bias;
  const u16 *addsrc;
  int M, Mout, N, K;           // M = staging row extent (padded); Mout = C rows
  int lda, ldb, ldc;
  long long bsA, bsB, bsC;
};

__device__ __forceinline__ void gl2lds16(const u16* g, u16* l){
  __builtin_amdgcn_global_load_lds(
      (const __attribute__((address_space(1))) u32*)((const void*)g),
      (__attribute__((address_space(3))) u32*)((void*)l),
      16, 0, 0);
}

// slow (edge) staging: same swizzled layout, bounds-checked, zero-filled
__device__ __forceinline__ void stage_slow(u16* sT, const u16* g, long long ld,
                                           int row0, int rmax, int k0, int K, int tid){
  #pragma unroll
  for (int h = 0; h < 2; h++){
    int s = tid + h*256;
    int row = s >> 2;
    int col = (((s & 3) ^ ((s >> 3) & 3)) << 3);
    int grow = row0 + row;
    u16 v[8];
    #pragma unroll
    for (int e = 0; e < 8; e++){
      int gc = k0 + col + e;
      v[e] = (grow < rmax && gc < K) ? g[(long long)grow*ld + gc] : (u16)0;
    }
    *(uint4*)(sT + s*8) = *(const uint4*)v;
  }
}

template<int MODE, int EPI>
__global__ __launch_bounds__(256, (MODE==0) ? 4 : 2)
void g128(GemmP p){
  constexpr int NA = (MODE==0 || MODE==2) ? 1 : 2;
  constexpr int NB = (MODE==0 || MODE==3) ? 1 : 2;
  constexpr bool DUAL = (MODE >= 2);
  __shared__ u16 sA[NA][4096];
  __shared__ u16 sB[NB][4096];

  const int tid = threadIdx.x;
  const long long bz = blockIdx.z;
  const int row0 = blockIdx.y*128, col0 = blockIdx.x*128;
  const int lane = tid & 63, wid = tid >> 6;
  const int wr = wid >> 1, wc = wid & 1;
  const int quad = lane >> 4, l15 = lane & 15;

  const u16* Ag[NA]; const u16* Bg[NB];
  Ag[0] = p.A0 + bz*p.bsA;
  if (NA == 2) Ag[1] = p.A1 + bz*p.bsA;
  Bg[0] = p.B0 + bz*p.bsB;
  if (NB == 2) Bg[1] = p.B1 + bz*p.bsB;

  const int srow = tid >> 2;
  const int scol = (((tid & 3) ^ ((tid >> 3) & 3)) << 3);
  const bool fA = (row0 + 128 <= p.M);
  const bool fB = (col0 + 128 <= p.N);

  int aoff[4], boff[4];
  #pragma unroll
  for (int i=0;i<4;i++){
    int ar = wr*64 + i*16 + l15;
    aoff[i] = ar*32 + ((quad ^ ((ar>>1)&3))<<3);
    int br = wc*64 + i*16 + l15;
    boff[i] = br*32 + ((quad ^ ((br>>1)&3))<<3);
  }

  f32x4 acc0[4][4], acc1[4][4];
  #pragma unroll
  for (int i=0;i<4;i++)
    #pragma unroll
    for (int j=0;j<4;j++){
      acc0[i][j] = (f32x4){0.f,0.f,0.f,0.f};
      if (DUAL) acc1[i][j] = (f32x4){0.f,0.f,0.f,0.f};
    }

  for (int k0 = 0; k0 < p.K; k0 += 32){
    __syncthreads();
    const bool fk = (k0 + 32 <= p.K);
    #pragma unroll
    for (int t=0;t<NA;t++){
      if (fA && fk){
        const u16* g = Ag[t] + (long long)(row0 + srow)*p.lda + scol + k0;
        gl2lds16(g, &sA[t][tid*8]);
        gl2lds16(g + 64LL*p.lda, &sA[t][tid*8 + 2048]);
      } else stage_slow(&sA[t][0], Ag[t], p.lda, row0, p.M, k0, p.K, tid);
    }
    #pragma unroll
    for (int t=0;t<NB;t++){
      if (fB && fk){
        const u16* g = Bg[t] + (long long)(col0 + srow)*p.ldb + scol + k0;
        gl2lds16(g, &sB[t][tid*8]);
        gl2lds16(g + 64LL*p.ldb, &sB[t][tid*8 + 2048]);
      } else stage_slow(&sB[t][0], Bg[t], p.ldb, col0, p.N, k0, p.K, tid);
    }
    __syncthreads();

    bf16x8 a[NA][4], b[NB][4];
    #pragma unroll
    for (int t=0;t<NA;t++)
      #pragma unroll
      for (int i=0;i<4;i++) a[t][i] = *(const bf16x8*)&sA[t][aoff[i]];
    #pragma unroll
    for (int t=0;t<NB;t++)
      #pragma unroll
      for (int i=0;i<4;i++) b[t][i] = *(const bf16x8*)&sB[t][boff[i]];

    bf16x8 an[4];
    if (MODE == 4){
      #pragma unroll
      for (int i=0;i<4;i++){
        an[i] = a[1][i];
        u32* u = (u32*)&an[i];
        #pragma unroll
        for (int r=0;r<4;r++) u[r] ^= 0x80008000u;
      }
    }

    #pragma unroll
    for (int i=0;i<4;i++){
      #pragma unroll
      for (int j=0;j<4;j++){
        if (MODE == 0){
          acc0[i][j] = __builtin_amdgcn_mfma_f32_16x16x32_bf16(a[0][i], b[0][j], acc0[i][j], 0,0,0);
        } else if (MODE == 1){
          acc0[i][j] = __builtin_amdgcn_mfma_f32_16x16x32_bf16(a[0][i], b[0][j], acc0[i][j], 0,0,0);
          acc0[i][j] = __builtin_amdgcn_mfma_f32_16x16x32_bf16(a[1][i], b[1][j], acc0[i][j], 0,0,0);
        } else if (MODE == 2){
          acc0[i][j] = __builtin_amdgcn_mfma_f32_16x16x32_bf16(a[0][i], b[0][j], acc0[i][j], 0,0,0);
          acc1[i][j] = __builtin_amdgcn_mfma_f32_16x16x32_bf16(a[0][i], b[1][j], acc1[i][j], 0,0,0);
        } else if (MODE == 3){
          acc0[i][j] = __builtin_amdgcn_mfma_f32_16x16x32_bf16(a[0][i], b[0][j], acc0[i][j], 0,0,0);
          acc1[i][j] = __builtin_amdgcn_mfma_f32_16x16x32_bf16(a[1][i], b[0][j], acc1[i][j], 0,0,0);
        } else {
          acc0[i][j] = __builtin_amdgcn_mfma_f32_16x16x32_bf16(a[0][i], b[0][j], acc0[i][j], 0,0,0);
          acc0[i][j] = __builtin_amdgcn_mfma_f32_16x16x32_bf16(an[i],   b[1][j], acc0[i][j], 0,0,0);
          acc1[i][j] = __builtin_amdgcn_mfma_f32_16x16x32_bf16(a[0][i], b[1][j], acc1[i][j], 0,0,0);
          acc1[i][j] = __builtin_amdgcn_mfma_f32_16x16x32_bf16(a[1][i], b[0][j], acc1[i][j], 0,0,0);
        }
      }
    }
  }

  const long long cb = bz * p.bsC;
  #pragma unroll
  for (int i=0;i<4;i++){
    const int gr0 = row0 + wr*64 + i*16 + quad*4;
    #pragma unroll
    for (int j=0;j<4;j++){
      const int gc = col0 + wc*64 + j*16 + l15;
      if (gc >= p.N) continue;
      const float bval = (EPI==2 || EPI==3) ? p.bias[gc] : 0.0f;
      #pragma unroll
      for (int r=0;r<4;r++){
        const int gr = gr0 + r;
        if (gr >= p.Mout) continue;
        const long long ci = cb + (long long)gr * p.ldc + gc;
        float v = acc0[i][j][r];
        if (EPI==0){
          p.C0[ci] = f2b(v);
          if (DUAL) p.C1[ci] = f2b(acc1[i][j][r]);
        }
        else if (EPI==1) p.C0[ci] = f2b(gelu_fast(v));
        else if (EPI==2) p.C0[ci] = f2b(gelu_fast(v + bval));
        else             p.C0[ci] = f2b(gelu_fast(v + bval) + b2f(p.addsrc[ci]));
      }
    }
  }
}

// ---------------- instance-norm reduction + final epilogue ----------------
__global__ __launch_bounds__(256) void k_red(const u16* __restrict__ y2,
                                             float* __restrict__ gs, float* __restrict__ gss){
  int t = threadIdx.x;
  long long r0 = (long long)blockIdx.x * 256;
  float s = 0.f, ss = 0.f;
  for (int r=0;r<256;r++){
    float v = b2f(y2[(r0 + r)*256 + t]);
    s += v; ss += v*v;
  }
  atomicAdd(&gs[t], s);
  atomicAdd(&gss[t], ss);
}
// out[c,j,n] = (y2[n,j,c]-mu)*rsqrt(var+eps)*gamma + beta + x[c,j,n]
__global__ __launch_bounds__(256) void k_out(const u16* __restrict__ y2, const float* __restrict__ x,
                                             const float* __restrict__ gs, const float* __restrict__ gss,
                                             const float* __restrict__ gamma, const float* __restrict__ beta,
                                             float* __restrict__ out){
  __shared__ float tile[32][33];
  const int j = blockIdx.z;
  const int n0 = blockIdx.x*32, c0 = blockIdx.y*32;
  const int tx = threadIdx.x & 31, ty = threadIdx.x >> 5;
  #pragma unroll
  for (int nn = ty; nn < 32; nn += 8){
    int n = n0 + nn, c = c0 + tx;
    tile[nn][tx] = b2f(y2[(long long)n*65536 + j*256 + c]);
  }
  __syncthreads();
  #pragma unroll
  for (int cc = ty; cc < 32; cc += 8){
    int c = c0 + cc, n = n0 + tx;
    float mu = gs[c]*(1.0f/131072.0f);
    float var = gss[c]*(1.0f/131072.0f) - mu*mu;
    float rs = rsqrtf(var + 1e-3f);
    long long oi = (long long)c*131072 + (long long)j*512 + n;
    out[oi] = (tile[tx][cc] - mu)*rs*gamma[c] + beta[c] + x[oi];
  }
}

// ---------------- host ----------------
extern "C" void kernel_launch(void* const* d_in, const int* in_sizes, int n_in,
                              void* d_out, int out_size, void* d_ws, size_t ws_size,
                              hipStream_t stream){
  (void)in_sizes; (void)n_in; (void)out_size; (void)ws_size;
  const float* x     = (const float*)d_in[0];
  const float* legf  = (const float*)d_in[1];
  const float* wq    = (const float*)d_in[2];
  const float* w_r   = (const float*)d_in[3];
  const float* w_i   = (const float*)d_in[4];
  const float* m1w1  = (const float*)d_in[5];
  const float* m1b1  = (const float*)d_in[6];
  const float* m1w2  = (const float*)d_in[7];
  const float* m1b2  = (const float*)d_in[8];
  const float* m2w1  = (const float*)d_in[9];
  const float* m2b1  = (const float*)d_in[10];
  const float* m2w2  = (const float*)d_in[11];
  const float* m2b2  = (const float*)d_in[12];
  const float* gamma = (const float*)d_in[13];
  const float* beta  = (const float*)d_in[14];

  char* ws = (char*)d_ws;
  // per-slot arena (all concurrent-lifetime maxima):
  const size_t SZ_SA = 67108864ULL;   // xT / addb
  const size_t SZ_SB = 67371008ULL;   // x_bf | hr3+hi3 | legT | g6 | y2
  const size_t SZ_SC = 69206016ULL;   // lw | xs3r+xs3i | Gr5+Gi5
  const size_t SZ_SD = 75497472ULL;   // Fr2+Fi2 | Wr2+Wi2 | xs4 | Gr6+Gi6 | h1/h2
  char* F  = ws;
  char* SA = ws + 4194304ULL;
  char* SB = SA + SZ_SA;
  char* SC = SB + SZ_SB;
  char* SD = SC + SZ_SC;              // end: ~283.4 MB

  u16* Tc   = (u16*)(F + 0x000000);   // 384x512
  u16* Ts   = (u16*)(F + 0x060000);
  u16* tabr = (u16*)(F + 0x0C0000);   // 512x288
  u16* tabi = (u16*)(F + 0x108000);
  u16* w1t  = (u16*)(F + 0x150000);
  u16* w2t  = (u16*)(F + 0x170000);
  u16* w3t  = (u16*)(F + 0x190000);
  u16* w4t  = (u16*)(F + 0x1B0000);
  float* gsum = (float*)(F + 0x1D0000);
  float* gssq = (float*)(F + 0x1D0400);

  const size_t HS = 33685504ULL;      // 257*65536*2
  u16* xT   = (u16*)SA;               // (n,j,c)
  u16* x_bf = (u16*)SB;               // (c,j,n)
  u16* lw   = (u16*)SC;               // (l,m,j)
  u16* Fr2  = (u16*)SD;               // (m,c,j)
  u16* Fi2  = (u16*)(SD + HS);
  u16* hr3  = (u16*)SB;               // (m,l,c)
  u16* hi3  = (u16*)(SB + HS);
  u16* Wr2  = (u16*)SD;               // (l,f,c)
  u16* Wi2  = (u16*)(SD + HS);
  u16* xs3r = (u16*)SC;               // (l,f,m) ld 264
  u16* xs3i = (u16*)(SC + 34603008ULL);
  u16* legT = (u16*)SB;               // (m,j,l)
  u16* xs4r = (u16*)SD;               // (m,f,l)
  u16* xs4i = (u16*)(SD + HS);
  u16* Gr5  = (u16*)SC;               // (m,f,j)
  u16* Gi5  = (u16*)(SC + HS);
  u16* Gr6  = (u16*)SD;               // (j,f,m) ld 288, m>=257 zero
  u16* Gi6  = (u16*)(SD + 37748736ULL);
  u16* g6   = (u16*)SB;               // (n,j,f)
  u16* h1   = (u16*)SD;               // (p,c)
  u16* addb = (u16*)SA;               // (p,c)
  u16* h2   = (u16*)SD;
  u16* y2   = (u16*)SB;               // (p,c)

  // --- precompute ---
  k_ftab<<<dim3(768), dim3(256), 0, stream>>>(Tc, Ts);
  k_itab<<<dim3(576), dim3(256), 0, stream>>>(tabr, tabi);
  tr_f32b<false><<<dim3(8,8,1), dim3(256), 0, stream>>>(m1w1, w1t, nullptr, 256,256, 256,0, 256,0);
  tr_f32b<false><<<dim3(8,8,1), dim3(256), 0, stream>>>(m1w2, w2t, nullptr, 256,256, 256,0, 256,0);
  tr_f32b<false><<<dim3(8,8,1), dim3(256), 0, stream>>>(m2w1, w3t, nullptr, 256,256, 256,0, 256,0);
  tr_f32b<false><<<dim3(8,8,1), dim3(256), 0, stream>>>(m2w2, w4t, nullptr, 256,256, 256,0, 256,0);
  tr_f32b<true><<<dim3(16,8,256), dim3(256), 0, stream>>>(x, xT, x_bf, 256,512, 131072,512, 65536,256);
  k_lw<<<dim3(65792), dim3(256), 0, stream>>>(legf, wq, lw, 256*257*256);

  // --- stage 1: rfft (fused re+im, shared B): Fr/Fi(m,c,j) = Tc/Ts(m,n) * x_bf^T ---
  {
    GemmP p{Tc, Ts, x_bf, nullptr, Fr2, Fi2, nullptr, nullptr,
            384, 257, 65536, 512, 512, 512, 65536, 0, 0, 0};
    g128<3,0><<<dim3(512,3,1), dim3(256), 0, stream>>>(p);
  }
  // --- stage 2: Legendre fwd (fused, shared A), batch m: h(m,l,c) = lw_m(l,j) * F_m(c,j)^T ---
  {
    GemmP p{lw, nullptr, Fr2, Fi2, hr3, hi3, nullptr, nullptr,
            256, 256, 256, 256, 65792, 256, 256, 256, 65536, 65536};
    g128<2,0><<<dim3(2,2,257), dim3(256), 0, stream>>>(p);
  }
  // --- filters (after F2 dead) ---
  k_interp<<<dim3(256,4), dim3(256), 0, stream>>>(w_r, w_i, Wr2, Wi2);
  // --- stage 3: complex filter, batch l: xs = W_l * h_l^H-ish (4-product fused) ---
  {
    GemmP p{Wr2, Wi2, hr3, hi3, xs3r, xs3i, nullptr, nullptr,
            256, 256, 257, 256, 256, 65536, 264, 65536, 256, 67584};
    g128<4,0><<<dim3(3,2,256), dim3(256), 0, stream>>>(p);
  }
  // --- legT (m,j,l) ---
  tr_f32b<false><<<dim3(8,8,257), dim3(256), 0, stream>>>(legf, legT, nullptr, 256,256, 65792,256, 256,65536);
  // --- xs (l,f,m) -> (m,f,l) ---
  tr_b16<<<dim3(9,8,256), dim3(256), 0, stream>>>(xs3r, xs4r, 256,256,257, 67584,264, 65536,256);
  tr_b16<<<dim3(9,8,256), dim3(256), 0, stream>>>(xs3i, xs4i, 256,256,257, 67584,264, 65536,256);
  // --- stage 4: Legendre inv (fused, shared B), batch m: G(m,f,j) = xs_m(f,l) * legT_m(j,l)^T ---
  {
    GemmP p{xs4r, xs4i, legT, nullptr, Gr5, Gi5, nullptr, nullptr,
            256, 256, 256, 256, 256, 256, 256, 65536, 65536, 65536};
    g128<3,0><<<dim3(2,2,257), dim3(256), 0, stream>>>(p);
  }
  // --- G (m,f,j) -> (j,f,m), zero-pad m to 288 ---
  tr_b16<<<dim3(8,9,256), dim3(256), 0, stream>>>(Gr5, Gr6, 257,288,256, 65536,256, 73728,288);
  tr_b16<<<dim3(8,9,256), dim3(256), 0, stream>>>(Gi5, Gi6, 257,288,256, 65536,256, 73728,288);
  // --- stage 5: irfft + gelu: g6(n, j*256+f) = gelu(tabr*Gr6^T + tabi*Gi6^T), K=288 all-fast ---
  {
    GemmP p{tabr, tabi, Gr6, Gi6, g6, nullptr, nullptr, nullptr,
            512, 512, 65536, 288, 288, 288, 65536, 0, 0, 0};
    g128<1,1><<<dim3(512,4,1), dim3(256), 0, stream>>>(p);
  }
  // --- MLP1 ---
  {
    GemmP p{xT, nullptr, w1t, nullptr, h1, nullptr, m1b1, nullptr,
            131072, 131072, 256, 256, 256, 256, 256, 0, 0, 0};
    g128<0,2><<<dim3(2,1024,1), dim3(256), 0, stream>>>(p);
    p.A0 = h1; p.B0 = w2t; p.C0 = addb; p.bias = m1b2; p.addsrc = g6;
    g128<0,3><<<dim3(2,1024,1), dim3(256), 0, stream>>>(p);
  }
  // --- MLP2 ---
  {
    GemmP p{addb, nullptr, w3t, nullptr, h2, nullptr, m2b1, nullptr,
            131072, 131072, 256, 256, 256, 256, 256, 0, 0, 0};
    g128<0,2><<<dim3(2,1024,1), dim3(256), 0, stream>>>(p);
    p.A0 = h2; p.B0 = w4t; p.C0 = y2; p.bias = m2b2;
    g128<0,2><<<dim3(2,1024,1), dim3(256), 0, stream>>>(p);
  }
  // --- instance norm + residual ---
  hipMemsetAsync(gsum, 0, 2048, stream);
  k_red<<<dim3(512), dim3(256), 0, stream>>>(y2, gsum, gssq);
  k_out<<<dim3(16,8,256), dim3(256), 0, stream>>>(y2, x, gsum, gssq, gamma, beta, (float*)d_out);
}

// Round 5
// 1175.128 us; speedup vs baseline: 1.1443x; 1.0928x over previous
//
#include <hip/hip_runtime.h>

// SFNO block on MI355X. All heavy stages as bf16 MFMA GEMMs (C = A * B^T),
// fp32 accumulate, 128x128 tiles, global_load_lds staging, XOR-swizzled LDS.
// Fused dual/complex product modes. Sizes: C=256, NLAT=256, NLON=512, L=256,
// M=257 (rfft rows padded to 384, irfft K padded to 288), NREF=64.
// R1: vectorized data-movement kernels (k_xprep, k_legT, k_lw, k_out, k_red).

typedef __bf16 bf16x8 __attribute__((ext_vector_type(8)));
typedef float f32x4 __attribute__((ext_vector_type(4)));
typedef unsigned short u16;
typedef unsigned int u32;

__device__ __forceinline__ u16 f2b(float f){
  u32 u = __float_as_uint(f);
  u32 r = (u + 0x7FFFu + ((u >> 16) & 1u)) >> 16;  // round-to-nearest-even
  return (u16)r;
}
__device__ __forceinline__ float b2f(u16 h){
  return __uint_as_float(((u32)h) << 16);
}
// tanh-form gelu: v*sigmoid(2u), u = sqrt(2/pi)*(v + 0.044715 v^3).
__device__ __forceinline__ float gelu_fast(float v){
  float u2 = v * (1.5957691216057308f + 0.07135481627260025f * v * v);  // 2u
  float e  = __expf(-u2);                       // e^{-2u}
  return v * __builtin_amdgcn_rcpf(1.0f + e);   // v * sigmoid(2u)
}

// ---------------- small precompute kernels ----------------

// forward DFT tables (384 x 512) bf16, rows >=257 zero: Tc=cos, Ts=-sin
__global__ __launch_bounds__(256) void k_ftab(u16* Tc, u16* Ts){
  int i = blockIdx.x*256 + threadIdx.x;
  if (i >= 384*512) return;
  int m = i >> 9, n = i & 511;
  if (m >= 257){ Tc[i]=0; Ts[i]=0; return; }
  int r = (m*n) & 511;
  float th = (float)r * (6.283185307179586f/512.0f);
  Tc[i] = f2b(cosf(th));
  Ts[i] = f2b(-sinf(th));
}
// inverse tables (512 x 288), cols >=257 zero. cm=1 for m in {0,256}, else 2; /512.
__global__ __launch_bounds__(256) void k_itab(u16* tr, u16* ti){
  int i = blockIdx.x*256 + threadIdx.x;
  if (i >= 512*288) return;
  int n = i / 288, m = i % 288;
  if (m >= 257){ tr[i]=0; ti[i]=0; return; }
  int r = (n*m) & 511;
  float th = (float)r * (6.283185307179586f/512.0f);
  float cm = (m==0 || m==256) ? (1.0f/512.0f) : (2.0f/512.0f);
  tr[i] = f2b(cm*cosf(th));
  ti[i] = f2b(-cm*sinf(th));
}
// lw[l,m,j] = legfuncs[l,m,j]*wquad[j] -> bf16, 8 elems/thread vectorized
__global__ __launch_bounds__(256) void k_lw(const float* __restrict__ leg,
                                            const float* __restrict__ wq,
                                            u16* __restrict__ lw, int total8){
  int i = blockIdx.x*256 + threadIdx.x;
  if (i >= total8) return;
  long long base = (long long)i * 8;
  float4 a = *(const float4*)(leg + base);
  float4 b = *(const float4*)(leg + base + 4);
  int j = (int)(base & 255);
  u16 o[8];
  o[0]=f2b(a.x*wq[j  ]); o[1]=f2b(a.y*wq[j+1]); o[2]=f2b(a.z*wq[j+2]); o[3]=f2b(a.w*wq[j+3]);
  o[4]=f2b(b.x*wq[j+4]); o[5]=f2b(b.y*wq[j+5]); o[6]=f2b(b.z*wq[j+6]); o[7]=f2b(b.w*wq[j+7]);
  *(uint4*)(lw + base) = *(const uint4*)o;
}
// x (c,j,n) fp32 -> xT (n,j,c) bf16 + x_bf (c,j,n) bf16. 64x64 (c,n) tiles per j.
__global__ __launch_bounds__(256) void k_xprep(const float* __restrict__ x,
                                               u16* __restrict__ xT, u16* __restrict__ x_bf){
  __shared__ u16 tile[64*64];
  const int j = blockIdx.z;
  const int n0 = blockIdx.x*64, c0 = blockIdx.y*64;
  const int t = threadIdx.x;
  #pragma unroll
  for (int r = 0; r < 4; r++){
    int idx = r*256 + t;            // 0..1023
    int cl = idx >> 4;              // 0..63
    int n4 = (idx & 15) * 4;        // 0..60
    long long off = ((long long)(c0+cl))*131072 + (long long)j*512 + n0 + n4;
    float4 v = *(const float4*)(x + off);
    u16 b[4] = { f2b(v.x), f2b(v.y), f2b(v.z), f2b(v.w) };
    *(unsigned long long*)(x_bf + off) = *(const unsigned long long*)b;
    int sw = ((n4 >> 2) & 7) << 3;  // constant over k (n4+k, k<4 shares n>>2)
    tile[(n4+0)*64 + (cl ^ sw)] = b[0];
    tile[(n4+1)*64 + (cl ^ sw)] = b[1];
    tile[(n4+2)*64 + (cl ^ sw)] = b[2];
    tile[(n4+3)*64 + (cl ^ sw)] = b[3];
  }
  __syncthreads();
  #pragma unroll
  for (int r = 0; r < 2; r++){
    int idx = r*256 + t;            // 0..511
    int nl = idx >> 3;              // 0..63
    int cq = (idx & 7) * 8;         // 0..56
    uint4 v = *(const uint4*)&tile[nl*64 + (cq ^ (((nl>>2)&7)<<3))];
    *(uint4*)(xT + ((long long)(n0+nl))*65536 + (long long)j*256 + c0 + cq) = v;
  }
}
// legf (l,m,j) fp32 -> legT (m,j,l) bf16. 64x64 (l,j) tiles per m. Same swizzle.
__global__ __launch_bounds__(256) void k_legT(const float* __restrict__ leg,
                                              u16* __restrict__ legT){
  __shared__ u16 tile[64*64];
  const int m = blockIdx.z;
  const int l0 = blockIdx.x*64, j0 = blockIdx.y*64;
  const int t = threadIdx.x;
  #pragma unroll
  for (int r = 0; r < 4; r++){
    int idx = r*256 + t;
    int ll = idx >> 4;              // 0..63
    int j4 = (idx & 15) * 4;        // 0..60
    float4 v = *(const float4*)(leg + ((long long)(l0+ll))*65792 + (long long)m*256 + j0 + j4);
    u16 b[4] = { f2b(v.x), f2b(v.y), f2b(v.z), f2b(v.w) };
    int sw = ((j4 >> 2) & 7) << 3;
    tile[(j4+0)*64 + (ll ^ sw)] = b[0];
    tile[(j4+1)*64 + (ll ^ sw)] = b[1];
    tile[(j4+2)*64 + (ll ^ sw)] = b[2];
    tile[(j4+3)*64 + (ll ^ sw)] = b[3];
  }
  __syncthreads();
  #pragma unroll
  for (int r = 0; r < 2; r++){
    int idx = r*256 + t;
    int jl = idx >> 3;
    int lq = (idx & 7) * 8;
    uint4 v = *(const uint4*)&tile[jl*64 + (lq ^ (((jl>>2)&7)<<3))];
    *(uint4*)(legT + (long long)m*65536 + (long long)(j0+jl)*256 + l0 + lq) = v;
  }
}

// ---------------- generic tiled transposes ----------------
__global__ __launch_bounds__(256)
void tr_f32b(const float* __restrict__ src, u16* __restrict__ dst,
             int R, int Cc, long long ir, long long ib, long long oc, long long ob){
  __shared__ float tile[32][33];
  const long long b = blockIdx.z;
  const int r0 = blockIdx.y*32, c0 = blockIdx.x*32;
  const int tx = threadIdx.x & 31, ty = threadIdx.x >> 5;
  const float* s = src + b*ib;
  #pragma unroll
  for (int rr = ty; rr < 32; rr += 8){
    int r = r0 + rr, c = c0 + tx;
    float v = 0.0f;
    if (r < R && c < Cc) v = s[(long long)r*ir + c];
    tile[rr][tx] = v;
  }
  __syncthreads();
  u16* d = dst + b*ob;
  #pragma unroll
  for (int cc = ty; cc < 32; cc += 8){
    int c = c0 + cc, r = r0 + tx;
    if (r < R && c < Cc) d[(long long)c*oc + r] = f2b(tile[tx][cc]);
  }
}
// bf16 transpose; zero-pads dst rows r in [R, Rpad)
__global__ __launch_bounds__(256)
void tr_b16(const u16* __restrict__ src, u16* __restrict__ dst,
            int R, int Rpad, int Cc, long long ir, long long ib, long long oc, long long ob){
  __shared__ u16 tile[32][34];
  const long long b = blockIdx.z;
  const int r0 = blockIdx.y*32, c0 = blockIdx.x*32;
  const int tx = threadIdx.x & 31, ty = threadIdx.x >> 5;
  const u16* s = src + b*ib;
  #pragma unroll
  for (int rr = ty; rr < 32; rr += 8){
    int r = r0 + rr, c = c0 + tx;
    tile[rr][tx] = (r < R && c < Cc) ? s[(long long)r*ir + c] : (u16)0;
  }
  __syncthreads();
  u16* d = dst + b*ob;
  #pragma unroll
  for (int cc = ty; cc < 32; cc += 8){
    int c = c0 + cc, r = r0 + tx;
    if (r < Rpad && c < Cc) d[(long long)c*oc + r] = tile[tx][cc];
  }
}

// interpolated filters, scaled by sqrt(1+l)/256, layout (l,f,c) bf16.
__global__ __launch_bounds__(256) void k_interp(const float* __restrict__ wr,
                                                const float* __restrict__ wi,
                                                u16* __restrict__ Wr2, u16* __restrict__ Wi2){
  __shared__ float sr[64][65], si[64][65];
  const int f = blockIdx.x;
  const int c0 = blockIdx.y * 64;
  const float* gr = wr + ((long long)f*256 + c0)*64;
  const float* gi = wi + ((long long)f*256 + c0)*64;
  for (int t = threadIdx.x*4; t < 4096; t += 1024){
    float4 vr = *(const float4*)(gr + t);
    float4 vi = *(const float4*)(gi + t);
    int cc = t >> 6, k = t & 63;
    sr[cc][k]=vr.x; sr[cc][k+1]=vr.y; sr[cc][k+2]=vr.z; sr[cc][k+3]=vr.w;
    si[cc][k]=vi.x; si[cc][k+1]=vi.y; si[cc][k+2]=vi.z; si[cc][k+3]=vi.w;
  }
  __syncthreads();
  const int lane_c = threadIdx.x & 63;
  const int lgrp = threadIdx.x >> 6;
  for (int l = lgrp; l < 256; l += 4){
    float pos = (float)l * (63.0f/255.0f);
    int i0 = min((int)pos, 62);
    float fr = pos - (float)i0;
    float s = sqrtf(1.0f + (float)l) * (1.0f/256.0f);
    long long o = (long long)l*65536 + f*256 + c0 + lane_c;
    Wr2[o] = f2b((sr[lane_c][i0]*(1.0f-fr) + sr[lane_c][i0+1]*fr)*s);
    Wi2[o] = f2b((si[lane_c][i0]*(1.0f-fr) + si[lane_c][i0+1]*fr)*s);
  }
}

// ---------------- the 128x128 GEMM ----------------
// MODE 0: C0 = A0*B0^T
// MODE 1: C0 = A0*B0^T + A1*B1^T
// MODE 2: C0 = A0*B0^T ; C1 = A0*B1^T          (shared A)
// MODE 3: C0 = A0*B0^T ; C1 = A1*B0^T          (shared B)
// MODE 4: C0 = A0*B0^T - A1*B1^T ; C1 = A0*B1^T + A1*B0^T   (complex)
// EPI 0: bf16 raw; 1: bf16 gelu(v); 2: bf16 gelu(v+bias); 3: bf16 gelu(v+bias)+addsrc
struct GemmP {
  const u16 *A0, *A1, *B0, *B1;
  u16 *C0, *C1;
  const float *bias;
  const u16 *addsrc;
  int M, Mout, N, K;           // M = staging row extent (padded); Mout = C rows
  int lda, ldb, ldc;
  long long bsA, bsB, bsC;
};

__device__ __forceinline__ void gl2lds16(const u16* g, u16* l){
  __builtin_amdgcn_global_load_lds(
      (const __attribute__((address_space(1))) u32*)((const void*)g),
      (__attribute__((address_space(3))) u32*)((void*)l),
      16, 0, 0);
}

// slow (edge) staging: same swizzled layout, bounds-checked, zero-filled
__device__ __forceinline__ void stage_slow(u16* sT, const u16* g, long long ld,
                                           int row0, int rmax, int k0, int K, int tid){
  #pragma unroll
  for (int h = 0; h < 2; h++){
    int s = tid + h*256;
    int row = s >> 2;
    int col = (((s & 3) ^ ((s >> 3) & 3)) << 3);
    int grow = row0 + row;
    u16 v[8];
    #pragma unroll
    for (int e = 0; e < 8; e++){
      int gc = k0 + col + e;
      v[e] = (grow < rmax && gc < K) ? g[(long long)grow*ld + gc] : (u16)0;
    }
    *(uint4*)(sT + s*8) = *(const uint4*)v;
  }
}

template<int MODE, int EPI>
__global__ __launch_bounds__(256, (MODE==0) ? 4 : 2)
void g128(GemmP p){
  constexpr int NA = (MODE==0 || MODE==2) ? 1 : 2;
  constexpr int NB = (MODE==0 || MODE==3) ? 1 : 2;
  constexpr bool DUAL = (MODE >= 2);
  __shared__ u16 sA[NA][4096];
  __shared__ u16 sB[NB][4096];

  const int tid = threadIdx.x;
  const long long bz = blockIdx.z;
  const int row0 = blockIdx.y*128, col0 = blockIdx.x*128;
  const int lane = tid & 63, wid = tid >> 6;
  const int wr = wid >> 1, wc = wid & 1;
  const int quad = lane >> 4, l15 = lane & 15;

  const u16* Ag[NA]; const u16* Bg[NB];
  Ag[0] = p.A0 + bz*p.bsA;
  if (NA == 2) Ag[1] = p.A1 + bz*p.bsA;
  Bg[0] = p.B0 + bz*p.bsB;
  if (NB == 2) Bg[1] = p.B1 + bz*p.bsB;

  const int srow = tid >> 2;
  const int scol = (((tid & 3) ^ ((tid >> 3) & 3)) << 3);
  const bool fA = (row0 + 128 <= p.M);
  const bool fB = (col0 + 128 <= p.N);

  int aoff[4], boff[4];
  #pragma unroll
  for (int i=0;i<4;i++){
    int ar = wr*64 + i*16 + l15;
    aoff[i] = ar*32 + ((quad ^ ((ar>>1)&3))<<3);
    int br = wc*64 + i*16 + l15;
    boff[i] = br*32 + ((quad ^ ((br>>1)&3))<<3);
  }

  f32x4 acc0[4][4], acc1[4][4];
  #pragma unroll
  for (int i=0;i<4;i++)
    #pragma unroll
    for (int j=0;j<4;j++){
      acc0[i][j] = (f32x4){0.f,0.f,0.f,0.f};
      if (DUAL) acc1[i][j] = (f32x4){0.f,0.f,0.f,0.f};
    }

  for (int k0 = 0; k0 < p.K; k0 += 32){
    __syncthreads();
    const bool fk = (k0 + 32 <= p.K);
    #pragma unroll
    for (int t=0;t<NA;t++){
      if (fA && fk){
        const u16* g = Ag[t] + (long long)(row0 + srow)*p.lda + scol + k0;
        gl2lds16(g, &sA[t][tid*8]);
        gl2lds16(g + 64LL*p.lda, &sA[t][tid*8 + 2048]);
      } else stage_slow(&sA[t][0], Ag[t], p.lda, row0, p.M, k0, p.K, tid);
    }
    #pragma unroll
    for (int t=0;t<NB;t++){
      if (fB && fk){
        const u16* g = Bg[t] + (long long)(col0 + srow)*p.ldb + scol + k0;
        gl2lds16(g, &sB[t][tid*8]);
        gl2lds16(g + 64LL*p.ldb, &sB[t][tid*8 + 2048]);
      } else stage_slow(&sB[t][0], Bg[t], p.ldb, col0, p.N, k0, p.K, tid);
    }
    __syncthreads();

    bf16x8 a[NA][4], b[NB][4];
    #pragma unroll
    for (int t=0;t<NA;t++)
      #pragma unroll
      for (int i=0;i<4;i++) a[t][i] = *(const bf16x8*)&sA[t][aoff[i]];
    #pragma unroll
    for (int t=0;t<NB;t++)
      #pragma unroll
      for (int i=0;i<4;i++) b[t][i] = *(const bf16x8*)&sB[t][boff[i]];

    bf16x8 an[4];
    if (MODE == 4){
      #pragma unroll
      for (int i=0;i<4;i++){
        an[i] = a[1][i];
        u32* u = (u32*)&an[i];
        #pragma unroll
        for (int r=0;r<4;r++) u[r] ^= 0x80008000u;
      }
    }

    #pragma unroll
    for (int i=0;i<4;i++){
      #pragma unroll
      for (int j=0;j<4;j++){
        if (MODE == 0){
          acc0[i][j] = __builtin_amdgcn_mfma_f32_16x16x32_bf16(a[0][i], b[0][j], acc0[i][j], 0,0,0);
        } else if (MODE == 1){
          acc0[i][j] = __builtin_amdgcn_mfma_f32_16x16x32_bf16(a[0][i], b[0][j], acc0[i][j], 0,0,0);
          acc0[i][j] = __builtin_amdgcn_mfma_f32_16x16x32_bf16(a[1][i], b[1][j], acc0[i][j], 0,0,0);
        } else if (MODE == 2){
          acc0[i][j] = __builtin_amdgcn_mfma_f32_16x16x32_bf16(a[0][i], b[0][j], acc0[i][j], 0,0,0);
          acc1[i][j] = __builtin_amdgcn_mfma_f32_16x16x32_bf16(a[0][i], b[1][j], acc1[i][j], 0,0,0);
        } else if (MODE == 3){
          acc0[i][j] = __builtin_amdgcn_mfma_f32_16x16x32_bf16(a[0][i], b[0][j], acc0[i][j], 0,0,0);
          acc1[i][j] = __builtin_amdgcn_mfma_f32_16x16x32_bf16(a[1][i], b[0][j], acc1[i][j], 0,0,0);
        } else {
          acc0[i][j] = __builtin_amdgcn_mfma_f32_16x16x32_bf16(a[0][i], b[0][j], acc0[i][j], 0,0,0);
          acc0[i][j] = __builtin_amdgcn_mfma_f32_16x16x32_bf16(an[i],   b[1][j], acc0[i][j], 0,0,0);
          acc1[i][j] = __builtin_amdgcn_mfma_f32_16x16x32_bf16(a[0][i], b[1][j], acc1[i][j], 0,0,0);
          acc1[i][j] = __builtin_amdgcn_mfma_f32_16x16x32_bf16(a[1][i], b[0][j], acc1[i][j], 0,0,0);
        }
      }
    }
  }

  const long long cb = bz * p.bsC;
  #pragma unroll
  for (int i=0;i<4;i++){
    const int gr0 = row0 + wr*64 + i*16 + quad*4;
    #pragma unroll
    for (int j=0;j<4;j++){
      const int gc = col0 + wc*64 + j*16 + l15;
      if (gc >= p.N) continue;
      const float bval = (EPI==2 || EPI==3) ? p.bias[gc] : 0.0f;
      #pragma unroll
      for (int r=0;r<4;r++){
        const int gr = gr0 + r;
        if (gr >= p.Mout) continue;
        const long long ci = cb + (long long)gr * p.ldc + gc;
        float v = acc0[i][j][r];
        if (EPI==0){
          p.C0[ci] = f2b(v);
          if (DUAL) p.C1[ci] = f2b(acc1[i][j][r]);
        }
        else if (EPI==1) p.C0[ci] = f2b(gelu_fast(v));
        else if (EPI==2) p.C0[ci] = f2b(gelu_fast(v + bval));
        else             p.C0[ci] = f2b(gelu_fast(v + bval) + b2f(p.addsrc[ci]));
      }
    }
  }
}

// ---------------- instance-norm reduction + final epilogue ----------------
// vectorized: 512 blocks x 256 rows; each thread owns 8 channels, uint4 loads.
__global__ __launch_bounds__(256) void k_red(const u16* __restrict__ y2,
                                             float* __restrict__ gs, float* __restrict__ gss){
  __shared__ float ls[8][260], lss[8][260];
  const int t = threadIdx.x;
  const int cb = (t & 31) * 8;
  const int rg = t >> 5;
  long long row0 = (long long)blockIdx.x * 256 + rg;
  float s[8], q[8];
  #pragma unroll
  for (int e=0;e<8;e++){ s[e]=0.f; q[e]=0.f; }
  for (int k = 0; k < 32; k++){
    uint4 v = *(const uint4*)(y2 + (row0 + (long long)k*8)*256 + cb);
    const u16* pv = (const u16*)&v;
    #pragma unroll
    for (int e=0;e<8;e++){ float f = b2f(pv[e]); s[e]+=f; q[e]+=f*f; }
  }
  #pragma unroll
  for (int e=0;e<8;e++){ ls[rg][cb+e]=s[e]; lss[rg][cb+e]=q[e]; }
  __syncthreads();
  float S = 0.f, Q = 0.f;
  #pragma unroll
  for (int g=0; g<8; g++){ S += ls[g][t]; Q += lss[g][t]; }
  atomicAdd(&gs[t], S);
  atomicAdd(&gss[t], Q);
}
// out[c,j,n] = y2[n,j,c]*a[c] + b[c] + x[c,j,n], a=rs*gamma, b=beta-mu*a.
// 64x64 (n,c) tiles per j; uint4 y2 loads, float4 x/out; swizzled LDS transpose.
__global__ __launch_bounds__(256) void k_out(const u16* __restrict__ y2, const float* __restrict__ x,
                                             const float* __restrict__ gs, const float* __restrict__ gss,
                                             const float* __restrict__ gamma, const float* __restrict__ beta,
                                             float* __restrict__ out){
  __shared__ float tile[64*64];
  __shared__ float sa[64], sb2[64];
  const int j = blockIdx.z;
  const int n0 = blockIdx.x*64, c0 = blockIdx.y*64;
  const int t = threadIdx.x;
  if (t < 64){
    int c = c0 + t;
    float mu = gs[c]*(1.0f/131072.0f);
    float var = gss[c]*(1.0f/131072.0f) - mu*mu;
    float a = rsqrtf(var + 1e-3f)*gamma[c];
    sa[t] = a; sb2[t] = beta[c] - mu*a;
  }
  #pragma unroll
  for (int r = 0; r < 2; r++){
    int idx = r*256 + t;
    int nl = idx >> 3, cq = (idx & 7)*8;
    uint4 v = *(const uint4*)(y2 + ((long long)(n0+nl))*65536 + (long long)j*256 + c0 + cq);
    const u16* pv = (const u16*)&v;
    #pragma unroll
    for (int e=0;e<8;e++){
      int c = cq + e;
      tile[c*64 + (nl ^ (c & 0x38))] = b2f(pv[e]);
    }
  }
  __syncthreads();
  #pragma unroll
  for (int r = 0; r < 4; r++){
    int idx = r*256 + t;
    int cl = idx >> 4, nq = (idx & 15)*4;
    float4 w = *(const float4*)&tile[cl*64 + (nq ^ (cl & 0x38))];
    float a = sa[cl], b = sb2[cl];
    long long oi = ((long long)(c0+cl))*131072 + (long long)j*512 + n0 + nq;
    float4 xv = *(const float4*)(x + oi);
    float4 o;
    o.x = w.x*a + b + xv.x;
    o.y = w.y*a + b + xv.y;
    o.z = w.z*a + b + xv.z;
    o.w = w.w*a + b + xv.w;
    *(float4*)(out + oi) = o;
  }
}

// ---------------- host ----------------
extern "C" void kernel_launch(void* const* d_in, const int* in_sizes, int n_in,
                              void* d_out, int out_size, void* d_ws, size_t ws_size,
                              hipStream_t stream){
  (void)in_sizes; (void)n_in; (void)out_size; (void)ws_size;
  const float* x     = (const float*)d_in[0];
  const float* legf  = (const float*)d_in[1];
  const float* wq    = (const float*)d_in[2];
  const float* w_r   = (const float*)d_in[3];
  const float* w_i   = (const float*)d_in[4];
  const float* m1w1  = (const float*)d_in[5];
  const float* m1b1  = (const float*)d_in[6];
  const float* m1w2  = (const float*)d_in[7];
  const float* m1b2  = (const float*)d_in[8];
  const float* m2w1  = (const float*)d_in[9];
  const float* m2b1  = (const float*)d_in[10];
  const float* m2w2  = (const float*)d_in[11];
  const float* m2b2  = (const float*)d_in[12];
  const float* gamma = (const float*)d_in[13];
  const float* beta  = (const float*)d_in[14];

  char* ws = (char*)d_ws;
  const size_t SZ_SA = 67108864ULL;   // xT / addb
  const size_t SZ_SB = 67371008ULL;   // x_bf | hr3+hi3 | legT | g6 | y2
  const size_t SZ_SC = 69206016ULL;   // lw | xs3r+xs3i | Gr5+Gi5
  const size_t SZ_SD = 75497472ULL;   // Fr2+Fi2 | Wr2+Wi2 | xs4 | Gr6+Gi6 | h1/h2
  char* F  = ws;
  char* SA = ws + 4194304ULL;
  char* SB = SA + SZ_SA;
  char* SC = SB + SZ_SB;
  char* SD = SC + SZ_SC;              // end: ~283.4 MB

  u16* Tc   = (u16*)(F + 0x000000);   // 384x512
  u16* Ts   = (u16*)(F + 0x060000);
  u16* tabr = (u16*)(F + 0x0C0000);   // 512x288
  u16* tabi = (u16*)(F + 0x108000);
  u16* w1t  = (u16*)(F + 0x150000);
  u16* w2t  = (u16*)(F + 0x170000);
  u16* w3t  = (u16*)(F + 0x190000);
  u16* w4t  = (u16*)(F + 0x1B0000);
  float* gsum = (float*)(F + 0x1D0000);
  float* gssq = (float*)(F + 0x1D0400);

  const size_t HS = 33685504ULL;      // 257*65536*2
  u16* xT   = (u16*)SA;               // (n,j,c)
  u16* x_bf = (u16*)SB;               // (c,j,n)
  u16* lw   = (u16*)SC;               // (l,m,j)
  u16* Fr2  = (u16*)SD;               // (m,c,j)
  u16* Fi2  = (u16*)(SD + HS);
  u16* hr3  = (u16*)SB;               // (m,l,c)
  u16* hi3  = (u16*)(SB + HS);
  u16* Wr2  = (u16*)SD;               // (l,f,c)
  u16* Wi2  = (u16*)(SD + HS);
  u16* xs3r = (u16*)SC;               // (l,f,m) ld 264
  u16* xs3i = (u16*)(SC + 34603008ULL);
  u16* legT = (u16*)SB;               // (m,j,l)
  u16* xs4r = (u16*)SD;               // (m,f,l)
  u16* xs4i = (u16*)(SD + HS);
  u16* Gr5  = (u16*)SC;               // (m,f,j)
  u16* Gi5  = (u16*)(SC + HS);
  u16* Gr6  = (u16*)SD;               // (j,f,m) ld 288, m>=257 zero
  u16* Gi6  = (u16*)(SD + 37748736ULL);
  u16* g6   = (u16*)SB;               // (n,j,f)
  u16* h1   = (u16*)SD;               // (p,c)
  u16* addb = (u16*)SA;               // (p,c)
  u16* h2   = (u16*)SD;
  u16* y2   = (u16*)SB;               // (p,c)

  // --- precompute ---
  k_ftab<<<dim3(768), dim3(256), 0, stream>>>(Tc, Ts);
  k_itab<<<dim3(576), dim3(256), 0, stream>>>(tabr, tabi);
  tr_f32b<<<dim3(8,8,1), dim3(256), 0, stream>>>(m1w1, w1t, 256,256, 256,0, 256,0);
  tr_f32b<<<dim3(8,8,1), dim3(256), 0, stream>>>(m1w2, w2t, 256,256, 256,0, 256,0);
  tr_f32b<<<dim3(8,8,1), dim3(256), 0, stream>>>(m2w1, w3t, 256,256, 256,0, 256,0);
  tr_f32b<<<dim3(8,8,1), dim3(256), 0, stream>>>(m2w2, w4t, 256,256, 256,0, 256,0);
  k_xprep<<<dim3(8,4,256), dim3(256), 0, stream>>>(x, xT, x_bf);
  k_lw<<<dim3(8224), dim3(256), 0, stream>>>(legf, wq, lw, 2105344);

  // --- stage 1: rfft (fused re+im, shared B): Fr/Fi(m,c,j) = Tc/Ts(m,n) * x_bf^T ---
  {
    GemmP p{Tc, Ts, x_bf, nullptr, Fr2, Fi2, nullptr, nullptr,
            384, 257, 65536, 512, 512, 512, 65536, 0, 0, 0};
    g128<3,0><<<dim3(512,3,1), dim3(256), 0, stream>>>(p);
  }
  // --- stage 2: Legendre fwd (fused, shared A), batch m: h(m,l,c) = lw_m(l,j) * F_m(c,j)^T ---
  {
    GemmP p{lw, nullptr, Fr2, Fi2, hr3, hi3, nullptr, nullptr,
            256, 256, 256, 256, 65792, 256, 256, 256, 65536, 65536};
    g128<2,0><<<dim3(2,2,257), dim3(256), 0, stream>>>(p);
  }
  // --- filters (after F2 dead) ---
  k_interp<<<dim3(256,4), dim3(256), 0, stream>>>(w_r, w_i, Wr2, Wi2);
  // --- stage 3: complex filter, batch l: xs = W_l * h_l (4-product fused) ---
  {
    GemmP p{Wr2, Wi2, hr3, hi3, xs3r, xs3i, nullptr, nullptr,
            256, 256, 257, 256, 256, 65536, 264, 65536, 256, 67584};
    g128<4,0><<<dim3(3,2,256), dim3(256), 0, stream>>>(p);
  }
  // --- legT (m,j,l) ---
  k_legT<<<dim3(4,4,257), dim3(256), 0, stream>>>(legf, legT);
  // --- xs (l,f,m) -> (m,f,l) ---
  tr_b16<<<dim3(9,8,256), dim3(256), 0, stream>>>(xs3r, xs4r, 256,256,257, 67584,264, 65536,256);
  tr_b16<<<dim3(9,8,256), dim3(256), 0, stream>>>(xs3i, xs4i, 256,256,257, 67584,264, 65536,256);
  // --- stage 4: Legendre inv (fused, shared B), batch m: G(m,f,j) = xs_m(f,l) * legT_m(j,l)^T ---
  {
    GemmP p{xs4r, xs4i, legT, nullptr, Gr5, Gi5, nullptr, nullptr,
            256, 256, 256, 256, 256, 256, 256, 65536, 65536, 65536};
    g128<3,0><<<dim3(2,2,257), dim3(256), 0, stream>>>(p);
  }
  // --- G (m,f,j) -> (j,f,m), zero-pad m to 288 ---
  tr_b16<<<dim3(8,9,256), dim3(256), 0, stream>>>(Gr5, Gr6, 257,288,256, 65536,256, 73728,288);
  tr_b16<<<dim3(8,9,256), dim3(256), 0, stream>>>(Gi5, Gi6, 257,288,256, 65536,256, 73728,288);
  // --- stage 5: irfft + gelu: g6(n, j*256+f) = gelu(tabr*Gr6^T + tabi*Gi6^T), K=288 all-fast ---
  {
    GemmP p{tabr, tabi, Gr6, Gi6, g6, nullptr, nullptr, nullptr,
            512, 512, 65536, 288, 288, 288, 65536, 0, 0, 0};
    g128<1,1><<<dim3(512,4,1), dim3(256), 0, stream>>>(p);
  }
  // --- MLP1 ---
  {
    GemmP p{xT, nullptr, w1t, nullptr, h1, nullptr, m1b1, nullptr,
            131072, 131072, 256, 256, 256, 256, 256, 0, 0, 0};
    g128<0,2><<<dim3(2,1024,1), dim3(256), 0, stream>>>(p);
    p.A0 = h1; p.B0 = w2t; p.C0 = addb; p.bias = m1b2; p.addsrc = g6;
    g128<0,3><<<dim3(2,1024,1), dim3(256), 0, stream>>>(p);
  }
  // --- MLP2 ---
  {
    GemmP p{addb, nullptr, w3t, nullptr, h2, nullptr, m2b1, nullptr,
            131072, 131072, 256, 256, 256, 256, 256, 0, 0, 0};
    g128<0,2><<<dim3(2,1024,1), dim3(256), 0, stream>>>(p);
    p.A0 = h2; p.B0 = w4t; p.C0 = y2; p.bias = m2b2;
    g128<0,2><<<dim3(2,1024,1), dim3(256), 0, stream>>>(p);
  }
  // --- instance norm + residual ---
  hipMemsetAsync(gsum, 0, 2048, stream);
  k_red<<<dim3(512), dim3(256), 0, stream>>>(y2, gsum, gssq);
  k_out<<<dim3(8,4,256), dim3(256), 0, stream>>>(y2, x, gsum, gssq, gamma, beta, (float*)d_out);
}